// Round 9
// baseline (148.207 us; speedup 1.0000x reference)
//
#include <hip/hip_runtime.h>
#include <hip/hip_fp16.h>
#include <math.h>

#define NN 100000
#define NE 1600000
#define F0 128
#define F1 64
#define F2 40
#define NB 256         // buckets = CSR-build blocks
#define BSZ 391        // nodes per bucket (391*256 = 100096 >= NN)
#define CAP2 8192      // bucket capacity (mean 6250, sigma 79 -> 24 sigma)
#define CHUNK 3125     // NE / 512 partition blocks
#define GEMM1_BLOCKS 1563   // ceil(NN/64)
#define PART_BLOCKS 512

typedef _Float16 f16x8 __attribute__((ext_vector_type(8)));
typedef _Float16 f16x4 __attribute__((ext_vector_type(4)));
typedef float f32x4 __attribute__((ext_vector_type(4)));

// ---------------- init: zero counters + W1^T / W2^T fp16 prep ----------------
__global__ __launch_bounds__(256) void k_init(const float* __restrict__ W1,
                                              const float* __restrict__ W2,
                                              _Float16* __restrict__ w1t,
                                              _Float16* __restrict__ w2t,
                                              int* __restrict__ bucketCnt) {
    int idx = blockIdx.x * 256 + threadIdx.x;
    if (idx <= NB) bucketCnt[idx] = 0;     // counts[256] + gCursor
    if (idx < 64 * 128) {                  // w1t[n][k], n<64, k<128
        int n = idx >> 7, k = idx & 127;
        w1t[idx] = (_Float16)W1[k * 64 + n];
    } else if (idx < 64 * 128 + 48 * 64) { // w2t[n][k], n<48 (pad), k<64
        int j = idx - 64 * 128;
        int n = j >> 6, k = j & 63;
        w2t[j] = (_Float16)(n < 40 ? W2[k * 40 + n] : 0.0f);
    }
}

// ---------------- fused: gemm1 (raw h, fp16) INTERLEAVED with edge partition ----
// Blocks b<2048 with (b&3)==3 are partition blocks (512); all others gemm1.
// Interleave => both populations co-resident per CU: streaming partition waves
// hide the MFMA blocks' memory latency (time ~ max, not sum).
// gemm1: A-fragments straight from global x (no LDS stage, no 2nd barrier);
// epilogue transposes acc through per-wave LDS -> 16B coalesced stores.
__global__ __launch_bounds__(256) void k_g1p(const float* __restrict__ x,
                                             const _Float16* __restrict__ w1t,
                                             const int* __restrict__ src,
                                             const int* __restrict__ dst,
                                             int* __restrict__ bucketCnt,
                                             unsigned* __restrict__ bucket,
                                             _Float16* __restrict__ hs) {
    __shared__ _Float16 wl[64][136];   // 17.4 KB  W1^T (B operand)
    __shared__ _Float16 st[64][72];    // 9.2 KB   per-wave store-transpose buf
    __shared__ int cnt[NB], base[NB];  // 2 KB     partition path
    const int tid = threadIdx.x;
    const int b = blockIdx.x;

    bool isPart = (b < 2048) && ((b & 3) == 3);
    if (!isPart) {
        // ---- GEMM1 path ----
        const int gb = (b < 2048) ? (b - ((b + 1) >> 2)) : (b - PART_BLOCKS);
        const int row0 = gb * 64;
        for (int i = tid; i < 1024; i += 256)       // stage W1^T: 1024 uint4
            *(uint4*)&wl[i >> 4][(i & 15) * 8] = ((const uint4*)w1t)[i];
        __syncthreads();

        const int wave = tid >> 6;
        const int lane = tid & 63;
        const int l16 = lane & 15;
        const int hi = lane >> 4;     // 0..3
        const int g8 = hi * 8;

        int gra = row0 + wave * 16 + l16; if (gra >= NN) gra = NN - 1;
        const float* xr = x + (size_t)gra * F0;

        f32x4 acc[4] = {{0,0,0,0},{0,0,0,0},{0,0,0,0},{0,0,0,0}};
        #pragma unroll
        for (int k0 = 0; k0 < F0; k0 += 32) {
            float4 v0 = *(const float4*)&xr[k0 + g8];
            float4 v1 = *(const float4*)&xr[k0 + g8 + 4];
            f16x8 a;
            a[0] = (_Float16)v0.x; a[1] = (_Float16)v0.y;
            a[2] = (_Float16)v0.z; a[3] = (_Float16)v0.w;
            a[4] = (_Float16)v1.x; a[5] = (_Float16)v1.y;
            a[6] = (_Float16)v1.z; a[7] = (_Float16)v1.w;
            #pragma unroll
            for (int ct = 0; ct < 4; ++ct) {
                f16x8 bb = *(f16x8*)&wl[ct * 16 + l16][k0 + g8];
                acc[ct] = __builtin_amdgcn_mfma_f32_16x16x32_f16(a, bb, acc[ct], 0, 0, 0);
            }
        }

        // transpose acc through per-wave LDS region (wave-exclusive rows)
        #pragma unroll
        for (int ct = 0; ct < 4; ++ct)
            #pragma unroll
            for (int j = 0; j < 4; ++j)
                st[wave * 16 + hi * 4 + j][ct * 16 + l16] = (_Float16)acc[ct][j];

        int rr = lane >> 2;            // row within wave tile
        int cc = lane & 3;             // 16-half chunk
        int grow = row0 + wave * 16 + rr;
        if (grow < NN) {
            uint4 w0 = *(uint4*)&st[wave * 16 + rr][cc * 16];
            uint4 w1 = *(uint4*)&st[wave * 16 + rr][cc * 16 + 8];
            *(uint4*)&hs[(size_t)grow * F1 + cc * 16] = w0;
            *(uint4*)&hs[(size_t)grow * F1 + cc * 16 + 8] = w1;
        }
    } else {
        // ---- partition path ----
        const int pb = b >> 2;         // 0..511
        cnt[tid] = 0;
        __syncthreads();
        const int e0 = pb * CHUNK;
        const int e1 = e0 + CHUNK;     // 512 * 3125 == NE exactly
        for (int e = e0 + tid; e < e1; e += 256)
            atomicAdd(&cnt[dst[e] / BSZ], 1);
        __syncthreads();
        base[tid] = atomicAdd(&bucketCnt[tid], cnt[tid]);
        cnt[tid] = 0;
        __syncthreads();
        for (int e = e0 + tid; e < e1; e += 256) {
            int d = dst[e];
            int bk = d / BSZ;
            int loc = d - bk * BSZ;
            int ofs = atomicAdd(&cnt[bk], 1);
            bucket[(size_t)bk * CAP2 + base[bk] + ofs] =
                ((unsigned)loc << 17) | (unsigned)src[e];
        }
    }
}

// ---------------- phase B: per-bucket CSR segment build ----------------
__global__ __launch_bounds__(512) void k_build(const int* __restrict__ bucketCnt,
                                               const unsigned* __restrict__ bucket,
                                               int* __restrict__ gCursor,
                                               int* __restrict__ rs,
                                               int* __restrict__ ce,
                                               int* __restrict__ csr,
                                               float* __restrict__ dinv) {
    __shared__ int cnt[512];
    __shared__ int sc[512];
    __shared__ int sh_base;

    const int tid = threadIdx.x;
    const int b = blockIdx.x;
    const int n0 = b * BSZ;
    const int nn = (NN - n0 < BSZ) ? (NN - n0) : BSZ;

    cnt[tid] = 0;
    __syncthreads();

    const int cntB = bucketCnt[b];
    const unsigned* bk = bucket + (size_t)b * CAP2;
    for (int idx = tid; idx < cntB; idx += 512)
        atomicAdd(&cnt[bk[idx] >> 17], 1);
    __syncthreads();

    sc[tid] = cnt[tid];
    __syncthreads();
    for (int off = 1; off < 512; off <<= 1) {
        int v = (tid >= off) ? sc[tid - off] : 0;
        __syncthreads();
        sc[tid] += v;
        __syncthreads();
    }

    const int T = sc[511];
    if (tid == 0) sh_base = atomicAdd(gCursor, T);
    __syncthreads();
    const int base = sh_base;

    if (tid < nn) {
        int c = cnt[tid];
        int excl = sc[tid] - c;
        rs[n0 + tid] = base + excl;
        ce[n0 + tid] = base + sc[tid];
        dinv[n0 + tid] = rsqrtf((float)(c + 1));   // +1 self-loop
        sc[tid] = excl;
    }
    cnt[tid] = 0;
    __syncthreads();

    for (int idx = tid; idx < cntB; idx += 512) {
        unsigned p = bk[idx];
        int l = (int)(p >> 17);
        int ofs = atomicAdd(&cnt[l], 1);
        csr[base + sc[l] + ofs] = (int)(p & 0x1FFFFu);
    }
}

// ---------------- fp16 scaled-accumulate helpers ----------------
__device__ __forceinline__ void acc8s(float a[8], uint4 u, float s) {
    __half2 h0 = *(__half2*)&u.x, h1 = *(__half2*)&u.y;
    __half2 h2 = *(__half2*)&u.z, h3 = *(__half2*)&u.w;
    float2 f0 = __half22float2(h0), f1 = __half22float2(h1);
    float2 f2 = __half22float2(h2), f3 = __half22float2(h3);
    a[0] = fmaf(s, f0.x, a[0]); a[1] = fmaf(s, f0.y, a[1]);
    a[2] = fmaf(s, f1.x, a[2]); a[3] = fmaf(s, f1.y, a[3]);
    a[4] = fmaf(s, f2.x, a[4]); a[5] = fmaf(s, f2.y, a[5]);
    a[6] = fmaf(s, f3.x, a[6]); a[7] = fmaf(s, f3.y, a[7]);
}

__device__ __forceinline__ void acc4(float a[4], uint2 u) {
    __half2 h0 = *(__half2*)&u.x, h1 = *(__half2*)&u.y;
    float2 f0 = __half22float2(h0), f1 = __half22float2(h1);
    a[0] += f0.x; a[1] += f0.y; a[2] += f1.x; a[3] += f1.y;
}

// ---------------- fused gather1 + GEMM2 ----------------
__global__ __launch_bounds__(512) void k_fuse(const int* __restrict__ rs,
                                              const int* __restrict__ ce,
                                              const int* __restrict__ csr,
                                              const _Float16* __restrict__ hs,
                                              const float* __restrict__ dinv,
                                              const float* __restrict__ b1,
                                              const _Float16* __restrict__ w2t,
                                              _Float16* __restrict__ hs2) {
    __shared__ _Float16 al[64][72];    // 9.2 KB (+8 pad)
    __shared__ _Float16 wl2[48][72];   // 6.9 KB
    const int tid = threadIdx.x;
    const int row0 = blockIdx.x * 64;

    if (tid < 384)   // stage W2^T: 384 uint4 (consumed after the barrier)
        *(uint4*)&wl2[tid >> 3][(tid & 7) * 8] = ((const uint4*)w2t)[tid];

    // ---- phase 1: gather ----
    {
        int r = tid >> 3, g = tid & 7;
        int i = row0 + r; if (i >= NN) i = NN - 1;   // dup rows; writes guarded later
        const __half* hsh = (const __half*)hs;
        float dvi = dinv[i];
        float acc[8] = {0, 0, 0, 0, 0, 0, 0, 0};
        acc8s(acc, *(const uint4*)&hsh[(size_t)i * F1 + g * 8], dvi);  // self-loop
        int k = rs[i], end = ce[i];
        for (; k + 4 <= end; k += 4) {
            int s0 = csr[k], s1 = csr[k + 1], s2 = csr[k + 2], s3 = csr[k + 3];
            float d0 = dinv[s0], d1 = dinv[s1], d2 = dinv[s2], d3 = dinv[s3];
            uint4 u0 = *(const uint4*)&hsh[(size_t)s0 * F1 + g * 8];
            uint4 u1 = *(const uint4*)&hsh[(size_t)s1 * F1 + g * 8];
            uint4 u2 = *(const uint4*)&hsh[(size_t)s2 * F1 + g * 8];
            uint4 u3 = *(const uint4*)&hsh[(size_t)s3 * F1 + g * 8];
            acc8s(acc, u0, d0); acc8s(acc, u1, d1);
            acc8s(acc, u2, d2); acc8s(acc, u3, d3);
        }
        for (; k < end; ++k) {
            int s0 = csr[k];
            acc8s(acc, *(const uint4*)&hsh[(size_t)s0 * F1 + g * 8], dinv[s0]);
        }
        float4 c0 = *(const float4*)&b1[g * 8];
        float4 c1 = *(const float4*)&b1[g * 8 + 4];
        f16x8 o;
        o[0] = (_Float16)fmaxf(fmaf(dvi, acc[0], c0.x), 0.0f);
        o[1] = (_Float16)fmaxf(fmaf(dvi, acc[1], c0.y), 0.0f);
        o[2] = (_Float16)fmaxf(fmaf(dvi, acc[2], c0.z), 0.0f);
        o[3] = (_Float16)fmaxf(fmaf(dvi, acc[3], c0.w), 0.0f);
        o[4] = (_Float16)fmaxf(fmaf(dvi, acc[4], c1.x), 0.0f);
        o[5] = (_Float16)fmaxf(fmaf(dvi, acc[5], c1.y), 0.0f);
        o[6] = (_Float16)fmaxf(fmaf(dvi, acc[6], c1.z), 0.0f);
        o[7] = (_Float16)fmaxf(fmaf(dvi, acc[7], c1.w), 0.0f);
        *(f16x8*)&al[r][g * 8] = o;
    }
    __syncthreads();

    // ---- phase 2: MFMA a1 @ W2^T ----
    const int wave = tid >> 6;
    const int lane = tid & 63;
    const int l16 = lane & 15;
    const int g8 = (lane >> 4) * 8;

    for (int t = wave; t < 12; t += 8) {   // 12 tiles: 4 row x 3 col
        int rt = t / 3, ct = t - rt * 3;
        f32x4 acc = {0, 0, 0, 0};
        #pragma unroll
        for (int k0 = 0; k0 < F1; k0 += 32) {
            f16x8 a = *(f16x8*)&al[rt * 16 + l16][k0 + g8];
            f16x8 b = *(f16x8*)&wl2[ct * 16 + l16][k0 + g8];
            acc = __builtin_amdgcn_mfma_f32_16x16x32_f16(a, b, acc, 0, 0, 0);
        }
        int col = ct * 16 + l16;
        int baserow = row0 + rt * 16 + (lane >> 4) * 4;
        if (col < F2) {
            #pragma unroll
            for (int j = 0; j < 4; ++j) {
                int gr = baserow + j;
                if (gr < NN)
                    hs2[(size_t)gr * F2 + col] = (_Float16)(acc[j] * dinv[gr]);
            }
        }
    }
}

// ---------------- gather2: out = dinv*(hs2[i] + sum_nbr hs2[s]) + b2 ----------------
__global__ __launch_bounds__(320) void k_gather2(const int* __restrict__ rs,
                                                 const int* __restrict__ ce,
                                                 const int* __restrict__ csr,
                                                 const __half* __restrict__ hs2,
                                                 const float* __restrict__ dinv,
                                                 const float* __restrict__ b,
                                                 float* __restrict__ outp) {
    int t = blockIdx.x * 320 + threadIdx.x;   // t < 1,000,000 exact
    int i = t / 10;
    int g = t - i * 10;
    float acc[4] = {0, 0, 0, 0};
    acc4(acc, *(const uint2*)&hs2[(size_t)i * F2 + g * 4]);   // self-loop
    int k = rs[i], end = ce[i];
    for (; k + 4 <= end; k += 4) {
        int s0 = csr[k], s1 = csr[k + 1], s2 = csr[k + 2], s3 = csr[k + 3];
        uint2 u0 = *(const uint2*)&hs2[(size_t)s0 * F2 + g * 4];
        uint2 u1 = *(const uint2*)&hs2[(size_t)s1 * F2 + g * 4];
        uint2 u2 = *(const uint2*)&hs2[(size_t)s2 * F2 + g * 4];
        uint2 u3 = *(const uint2*)&hs2[(size_t)s3 * F2 + g * 4];
        acc4(acc, u0); acc4(acc, u1); acc4(acc, u2); acc4(acc, u3);
    }
    for (; k < end; ++k)
        acc4(acc, *(const uint2*)&hs2[(size_t)csr[k] * F2 + g * 4]);

    float dv = dinv[i];
    float4 bb = *(const float4*)&b[g * 4];
    float4 r;
    r.x = fmaf(dv, acc[0], bb.x);
    r.y = fmaf(dv, acc[1], bb.y);
    r.z = fmaf(dv, acc[2], bb.z);
    r.w = fmaf(dv, acc[3], bb.w);
    *(float4*)&outp[(size_t)i * F2 + g * 4] = r;
}

extern "C" void kernel_launch(void* const* d_in, const int* in_sizes, int n_in,
                              void* d_out, int out_size, void* d_ws, size_t ws_size,
                              hipStream_t stream) {
    const float* x  = (const float*)d_in[0];
    const int*   ei = (const int*)d_in[1];
    const float* W1 = (const float*)d_in[2];
    const float* b1 = (const float*)d_in[3];
    const float* W2 = (const float*)d_in[4];
    const float* b2 = (const float*)d_in[5];
    float* out = (float*)d_out;

    const int* src = ei;
    const int* dst = ei + NE;

    // workspace layout in 4-byte units (~29 MB):
    // [dinv 102400][rs 102400][ce 102400][bucketCnt 1024][w1t 4096][w2t 1536]
    // [csr 1.6M][hs 3.2M (NN*64 fp16)][bucket 2.1M]
    // hs2 (NN*40 fp16 = 8 MB) aliases bucket (consumed by k_build first).
    float*    dinv      = (float*)d_ws;
    int*      rs        = (int*)d_ws + 102400;
    int*      ce        = (int*)d_ws + 204800;
    int*      bucketCnt = (int*)d_ws + 307200;    // [0..255]=counts, [256]=gCursor
    _Float16* w1t       = (_Float16*)((int*)d_ws + 308224);  // 8192 halfs
    _Float16* w2t       = (_Float16*)((int*)d_ws + 312320);  // 3072 halfs
    int*      csr       = (int*)d_ws + 313856;
    _Float16* hs        = (_Float16*)((int*)d_ws + 313856 + NE);   // NN*64 fp16
    unsigned* bucket    = (unsigned*)((int*)d_ws + 313856 + NE + 3200000);
    _Float16* hs2       = (_Float16*)bucket;

    // 1: zero counters + fp16 transposed weights
    k_init<<<44, 256, 0, stream>>>(W1, W2, w1t, w2t, bucketCnt);
    // 2: gemm1 (raw h) interleaved with edge partition — co-resident overlap
    k_g1p<<<GEMM1_BLOCKS + PART_BLOCKS, 256, 0, stream>>>(x, w1t, src, dst,
                                                          bucketCnt, bucket, hs);
    // 3: CSR segments + dinv
    k_build<<<NB, 512, 0, stream>>>(bucketCnt, bucket, bucketCnt + NB,
                                    rs, ce, csr, dinv);
    // 4: gather1 (+dinv[src] scaling) fused with gemm2
    k_fuse<<<GEMM1_BLOCKS, 512, 0, stream>>>(rs, ce, csr, hs, dinv, b1, w2t, hs2);
    // 5: gather2 -> out
    k_gather2<<<NN / 32, 320, 0, stream>>>(rs, ce, csr, (const __half*)hs2,
                                           dinv, b2, out);
}

// Round 10
// 130.977 us; speedup vs baseline: 1.1316x; 1.1316x over previous
//
#include <hip/hip_runtime.h>
#include <hip/hip_fp16.h>
#include <math.h>

#define NN 100000
#define NE 1600000
#define F0 128
#define F1 64
#define F2 40
#define NB 256         // buckets = CSR-build blocks
#define BSZ 391        // nodes per bucket (391*256 = 100096 >= NN)
#define CAP2 8192      // bucket capacity (mean 6250, sigma 79 -> 24 sigma)
#define CHUNK 3125     // NE / 512 partition blocks
#define GEMM1_BLOCKS 1563   // ceil(NN/64)
#define PART_BLOCKS 512

typedef _Float16 f16x8 __attribute__((ext_vector_type(8)));
typedef _Float16 f16x4 __attribute__((ext_vector_type(4)));
typedef float f32x4 __attribute__((ext_vector_type(4)));

// ---------------- init: zero counters + W1^T / W2^T fp16 prep ----------------
__global__ __launch_bounds__(256) void k_init(const float* __restrict__ W1,
                                              const float* __restrict__ W2,
                                              _Float16* __restrict__ w1t,
                                              _Float16* __restrict__ w2t,
                                              int* __restrict__ bucketCnt) {
    int idx = blockIdx.x * 256 + threadIdx.x;
    if (idx <= NB) bucketCnt[idx] = 0;     // counts[256] + gCursor
    if (idx < 64 * 128) {                  // w1t[n][k], n<64, k<128
        int n = idx >> 7, k = idx & 127;
        w1t[idx] = (_Float16)W1[k * 64 + n];
    } else if (idx < 64 * 128 + 48 * 64) { // w2t[n][k], n<48 (pad), k<64
        int j = idx - 64 * 128;
        int n = j >> 6, k = j & 63;
        w2t[j] = (_Float16)(n < 40 ? W2[k * 40 + n] : 0.0f);
    }
}

// ---------------- fused: gemm1 (raw h, fp16) || 256-bucket edge partition --------
// blocks [0,1563): hs = x @ W1 (round-8 proven structure: LDS-staged x).
// blocks [1563,2075): partition edges (concentrated tail burst -> dense bucket
// line accumulation in L2; round-9 uniform interleave cost +16MB writeback).
// CHANGE vs round 8 (single variable): epilogue transposes acc through the
// dead xl buffer -> 2x16B coalesced hs stores instead of 16x2B scattered.
__global__ __launch_bounds__(256) void k_g1p(const float* __restrict__ x,
                                             const _Float16* __restrict__ w1t,
                                             const int* __restrict__ src,
                                             const int* __restrict__ dst,
                                             int* __restrict__ bucketCnt,
                                             unsigned* __restrict__ bucket,
                                             _Float16* __restrict__ hs) {
    __shared__ _Float16 xl[64][136];   // 17.4 KB; reused as store-transpose buf
    __shared__ _Float16 wl[64][136];   // 17.4 KB
    __shared__ int cnt[NB], base[NB];  // 2 KB (part path)
    const int tid = threadIdx.x;

    if (blockIdx.x < GEMM1_BLOCKS) {
        // ---- GEMM1 path ----
        const int row0 = blockIdx.x * 64;
        for (int i = tid; i < 1024; i += 256)        // stage W1^T: 1024 uint4
            *(uint4*)&wl[i >> 4][(i & 15) * 8] = ((const uint4*)w1t)[i];
        {   // stage x tile: 4 threads/row, 32 floats each, fp32->fp16 (coalesced)
            int r = tid >> 2, part = tid & 3;
            int gr = row0 + r; if (gr >= NN) gr = NN - 1;
            const float* xr = x + (size_t)gr * F0 + part * 32;
            _Float16* dstp = &xl[r][part * 32];
            #pragma unroll
            for (int q = 0; q < 8; ++q) {
                float4 v = *(const float4*)&xr[q * 4];
                f16x4 h;
                h[0] = (_Float16)v.x; h[1] = (_Float16)v.y;
                h[2] = (_Float16)v.z; h[3] = (_Float16)v.w;
                *(f16x4*)&dstp[q * 4] = h;
            }
        }
        __syncthreads();

        const int wave = tid >> 6;
        const int lane = tid & 63;
        const int l16 = lane & 15;
        const int hi = lane >> 4;     // 0..3
        const int g8 = hi * 8;

        f32x4 acc[4] = {{0,0,0,0},{0,0,0,0},{0,0,0,0},{0,0,0,0}};
        #pragma unroll
        for (int k0 = 0; k0 < F0; k0 += 32) {
            f16x8 a = *(f16x8*)&xl[wave * 16 + l16][k0 + g8];
            #pragma unroll
            for (int ct = 0; ct < 4; ++ct) {
                f16x8 b = *(f16x8*)&wl[ct * 16 + l16][k0 + g8];
                acc[ct] = __builtin_amdgcn_mfma_f32_16x16x32_f16(a, b, acc[ct], 0, 0, 0);
            }
        }

        __syncthreads();   // all xl reads complete -> safe to overwrite
        // transpose acc into xl rows [wave*16, wave*16+16): row=out-row, col=out-col
        #pragma unroll
        for (int ct = 0; ct < 4; ++ct)
            #pragma unroll
            for (int j = 0; j < 4; ++j)
                xl[wave * 16 + hi * 4 + j][ct * 16 + l16] = (_Float16)acc[ct][j];
        __syncthreads();   // transpose visible

        int rr = lane >> 2;            // row within wave tile (0..15)
        int cc = lane & 3;             // 16-half chunk (0..3)
        int grow = row0 + wave * 16 + rr;
        if (grow < NN) {
            uint4 w0 = *(uint4*)&xl[wave * 16 + rr][cc * 16];
            uint4 w1 = *(uint4*)&xl[wave * 16 + rr][cc * 16 + 8];
            *(uint4*)&hs[(size_t)grow * F1 + cc * 16] = w0;
            *(uint4*)&hs[(size_t)grow * F1 + cc * 16 + 8] = w1;
        }
    } else {
        // ---- partition path (tail burst, round-8 proven) ----
        const int pb = blockIdx.x - GEMM1_BLOCKS;
        cnt[tid] = 0;
        __syncthreads();
        const int e0 = pb * CHUNK;
        const int e1 = e0 + CHUNK;     // 512 * 3125 == NE exactly
        for (int e = e0 + tid; e < e1; e += 256)
            atomicAdd(&cnt[dst[e] / BSZ], 1);
        __syncthreads();
        base[tid] = atomicAdd(&bucketCnt[tid], cnt[tid]);
        cnt[tid] = 0;
        __syncthreads();
        for (int e = e0 + tid; e < e1; e += 256) {
            int d = dst[e];
            int bk = d / BSZ;
            int loc = d - bk * BSZ;
            int ofs = atomicAdd(&cnt[bk], 1);
            bucket[(size_t)bk * CAP2 + base[bk] + ofs] =
                ((unsigned)loc << 17) | (unsigned)src[e];
        }
    }
}

// ---------------- phase B: per-bucket CSR segment build ----------------
__global__ __launch_bounds__(512) void k_build(const int* __restrict__ bucketCnt,
                                               const unsigned* __restrict__ bucket,
                                               int* __restrict__ gCursor,
                                               int* __restrict__ rs,
                                               int* __restrict__ ce,
                                               int* __restrict__ csr,
                                               float* __restrict__ dinv) {
    __shared__ int cnt[512];
    __shared__ int sc[512];
    __shared__ int sh_base;

    const int tid = threadIdx.x;
    const int b = blockIdx.x;
    const int n0 = b * BSZ;
    const int nn = (NN - n0 < BSZ) ? (NN - n0) : BSZ;

    cnt[tid] = 0;
    __syncthreads();

    const int cntB = bucketCnt[b];
    const unsigned* bk = bucket + (size_t)b * CAP2;
    for (int idx = tid; idx < cntB; idx += 512)
        atomicAdd(&cnt[bk[idx] >> 17], 1);
    __syncthreads();

    sc[tid] = cnt[tid];
    __syncthreads();
    for (int off = 1; off < 512; off <<= 1) {
        int v = (tid >= off) ? sc[tid - off] : 0;
        __syncthreads();
        sc[tid] += v;
        __syncthreads();
    }

    const int T = sc[511];
    if (tid == 0) sh_base = atomicAdd(gCursor, T);
    __syncthreads();
    const int base = sh_base;

    if (tid < nn) {
        int c = cnt[tid];
        int excl = sc[tid] - c;
        rs[n0 + tid] = base + excl;
        ce[n0 + tid] = base + sc[tid];
        dinv[n0 + tid] = rsqrtf((float)(c + 1));   // +1 self-loop
        sc[tid] = excl;
    }
    cnt[tid] = 0;
    __syncthreads();

    for (int idx = tid; idx < cntB; idx += 512) {
        unsigned p = bk[idx];
        int l = (int)(p >> 17);
        int ofs = atomicAdd(&cnt[l], 1);
        csr[base + sc[l] + ofs] = (int)(p & 0x1FFFFu);
    }
}

// ---------------- fp16 scaled-accumulate helpers ----------------
__device__ __forceinline__ void acc8s(float a[8], uint4 u, float s) {
    __half2 h0 = *(__half2*)&u.x, h1 = *(__half2*)&u.y;
    __half2 h2 = *(__half2*)&u.z, h3 = *(__half2*)&u.w;
    float2 f0 = __half22float2(h0), f1 = __half22float2(h1);
    float2 f2 = __half22float2(h2), f3 = __half22float2(h3);
    a[0] = fmaf(s, f0.x, a[0]); a[1] = fmaf(s, f0.y, a[1]);
    a[2] = fmaf(s, f1.x, a[2]); a[3] = fmaf(s, f1.y, a[3]);
    a[4] = fmaf(s, f2.x, a[4]); a[5] = fmaf(s, f2.y, a[5]);
    a[6] = fmaf(s, f3.x, a[6]); a[7] = fmaf(s, f3.y, a[7]);
}

__device__ __forceinline__ void acc4(float a[4], uint2 u) {
    __half2 h0 = *(__half2*)&u.x, h1 = *(__half2*)&u.y;
    float2 f0 = __half22float2(h0), f1 = __half22float2(h1);
    a[0] += f0.x; a[1] += f0.y; a[2] += f1.x; a[3] += f1.y;
}

// ---------------- fused gather1 + GEMM2 ----------------
__global__ __launch_bounds__(512) void k_fuse(const int* __restrict__ rs,
                                              const int* __restrict__ ce,
                                              const int* __restrict__ csr,
                                              const _Float16* __restrict__ hs,
                                              const float* __restrict__ dinv,
                                              const float* __restrict__ b1,
                                              const _Float16* __restrict__ w2t,
                                              _Float16* __restrict__ hs2) {
    __shared__ _Float16 al[64][72];    // 9.2 KB (+8 pad)
    __shared__ _Float16 wl2[48][72];   // 6.9 KB
    const int tid = threadIdx.x;
    const int row0 = blockIdx.x * 64;

    if (tid < 384)   // stage W2^T: 384 uint4 (consumed after the barrier)
        *(uint4*)&wl2[tid >> 3][(tid & 7) * 8] = ((const uint4*)w2t)[tid];

    // ---- phase 1: gather ----
    {
        int r = tid >> 3, g = tid & 7;
        int i = row0 + r; if (i >= NN) i = NN - 1;   // dup rows; writes guarded later
        const __half* hsh = (const __half*)hs;
        float dvi = dinv[i];
        float acc[8] = {0, 0, 0, 0, 0, 0, 0, 0};
        acc8s(acc, *(const uint4*)&hsh[(size_t)i * F1 + g * 8], dvi);  // self-loop
        int k = rs[i], end = ce[i];
        for (; k + 4 <= end; k += 4) {
            int s0 = csr[k], s1 = csr[k + 1], s2 = csr[k + 2], s3 = csr[k + 3];
            float d0 = dinv[s0], d1 = dinv[s1], d2 = dinv[s2], d3 = dinv[s3];
            uint4 u0 = *(const uint4*)&hsh[(size_t)s0 * F1 + g * 8];
            uint4 u1 = *(const uint4*)&hsh[(size_t)s1 * F1 + g * 8];
            uint4 u2 = *(const uint4*)&hsh[(size_t)s2 * F1 + g * 8];
            uint4 u3 = *(const uint4*)&hsh[(size_t)s3 * F1 + g * 8];
            acc8s(acc, u0, d0); acc8s(acc, u1, d1);
            acc8s(acc, u2, d2); acc8s(acc, u3, d3);
        }
        for (; k < end; ++k) {
            int s0 = csr[k];
            acc8s(acc, *(const uint4*)&hsh[(size_t)s0 * F1 + g * 8], dinv[s0]);
        }
        float4 c0 = *(const float4*)&b1[g * 8];
        float4 c1 = *(const float4*)&b1[g * 8 + 4];
        f16x8 o;
        o[0] = (_Float16)fmaxf(fmaf(dvi, acc[0], c0.x), 0.0f);
        o[1] = (_Float16)fmaxf(fmaf(dvi, acc[1], c0.y), 0.0f);
        o[2] = (_Float16)fmaxf(fmaf(dvi, acc[2], c0.z), 0.0f);
        o[3] = (_Float16)fmaxf(fmaf(dvi, acc[3], c0.w), 0.0f);
        o[4] = (_Float16)fmaxf(fmaf(dvi, acc[4], c1.x), 0.0f);
        o[5] = (_Float16)fmaxf(fmaf(dvi, acc[5], c1.y), 0.0f);
        o[6] = (_Float16)fmaxf(fmaf(dvi, acc[6], c1.z), 0.0f);
        o[7] = (_Float16)fmaxf(fmaf(dvi, acc[7], c1.w), 0.0f);
        *(f16x8*)&al[r][g * 8] = o;
    }
    __syncthreads();

    // ---- phase 2: MFMA a1 @ W2^T ----
    const int wave = tid >> 6;
    const int lane = tid & 63;
    const int l16 = lane & 15;
    const int g8 = (lane >> 4) * 8;

    for (int t = wave; t < 12; t += 8) {   // 12 tiles: 4 row x 3 col
        int rt = t / 3, ct = t - rt * 3;
        f32x4 acc = {0, 0, 0, 0};
        #pragma unroll
        for (int k0 = 0; k0 < F1; k0 += 32) {
            f16x8 a = *(f16x8*)&al[rt * 16 + l16][k0 + g8];
            f16x8 b = *(f16x8*)&wl2[ct * 16 + l16][k0 + g8];
            acc = __builtin_amdgcn_mfma_f32_16x16x32_f16(a, b, acc, 0, 0, 0);
        }
        int col = ct * 16 + l16;
        int baserow = row0 + rt * 16 + (lane >> 4) * 4;
        if (col < F2) {
            #pragma unroll
            for (int j = 0; j < 4; ++j) {
                int gr = baserow + j;
                if (gr < NN)
                    hs2[(size_t)gr * F2 + col] = (_Float16)(acc[j] * dinv[gr]);
            }
        }
    }
}

// ---------------- gather2: out = dinv*(hs2[i] + sum_nbr hs2[s]) + b2 ----------------
__global__ __launch_bounds__(320) void k_gather2(const int* __restrict__ rs,
                                                 const int* __restrict__ ce,
                                                 const int* __restrict__ csr,
                                                 const __half* __restrict__ hs2,
                                                 const float* __restrict__ dinv,
                                                 const float* __restrict__ b,
                                                 float* __restrict__ outp) {
    int t = blockIdx.x * 320 + threadIdx.x;   // t < 1,000,000 exact
    int i = t / 10;
    int g = t - i * 10;
    float acc[4] = {0, 0, 0, 0};
    acc4(acc, *(const uint2*)&hs2[(size_t)i * F2 + g * 4]);   // self-loop
    int k = rs[i], end = ce[i];
    for (; k + 4 <= end; k += 4) {
        int s0 = csr[k], s1 = csr[k + 1], s2 = csr[k + 2], s3 = csr[k + 3];
        uint2 u0 = *(const uint2*)&hs2[(size_t)s0 * F2 + g * 4];
        uint2 u1 = *(const uint2*)&hs2[(size_t)s1 * F2 + g * 4];
        uint2 u2 = *(const uint2*)&hs2[(size_t)s2 * F2 + g * 4];
        uint2 u3 = *(const uint2*)&hs2[(size_t)s3 * F2 + g * 4];
        acc4(acc, u0); acc4(acc, u1); acc4(acc, u2); acc4(acc, u3);
    }
    for (; k < end; ++k)
        acc4(acc, *(const uint2*)&hs2[(size_t)csr[k] * F2 + g * 4]);

    float dv = dinv[i];
    float4 bb = *(const float4*)&b[g * 4];
    float4 r;
    r.x = fmaf(dv, acc[0], bb.x);
    r.y = fmaf(dv, acc[1], bb.y);
    r.z = fmaf(dv, acc[2], bb.z);
    r.w = fmaf(dv, acc[3], bb.w);
    *(float4*)&outp[(size_t)i * F2 + g * 4] = r;
}

extern "C" void kernel_launch(void* const* d_in, const int* in_sizes, int n_in,
                              void* d_out, int out_size, void* d_ws, size_t ws_size,
                              hipStream_t stream) {
    const float* x  = (const float*)d_in[0];
    const int*   ei = (const int*)d_in[1];
    const float* W1 = (const float*)d_in[2];
    const float* b1 = (const float*)d_in[3];
    const float* W2 = (const float*)d_in[4];
    const float* b2 = (const float*)d_in[5];
    float* out = (float*)d_out;

    const int* src = ei;
    const int* dst = ei + NE;

    // workspace layout in 4-byte units (~29 MB):
    // [dinv 102400][rs 102400][ce 102400][bucketCnt 1024][w1t 4096][w2t 1536]
    // [csr 1.6M][hs 3.2M (NN*64 fp16)][bucket 2.1M]
    // hs2 (NN*40 fp16 = 8 MB) aliases bucket (consumed by k_build first).
    float*    dinv      = (float*)d_ws;
    int*      rs        = (int*)d_ws + 102400;
    int*      ce        = (int*)d_ws + 204800;
    int*      bucketCnt = (int*)d_ws + 307200;    // [0..255]=counts, [256]=gCursor
    _Float16* w1t       = (_Float16*)((int*)d_ws + 308224);  // 8192 halfs
    _Float16* w2t       = (_Float16*)((int*)d_ws + 312320);  // 3072 halfs
    int*      csr       = (int*)d_ws + 313856;
    _Float16* hs        = (_Float16*)((int*)d_ws + 313856 + NE);   // NN*64 fp16
    unsigned* bucket    = (unsigned*)((int*)d_ws + 313856 + NE + 3200000);
    _Float16* hs2       = (_Float16*)bucket;

    // 1: zero counters + fp16 transposed weights
    k_init<<<44, 256, 0, stream>>>(W1, W2, w1t, w2t, bucketCnt);
    // 2: gemm1 (raw h) + edge partition (tail burst) — round-8 proven mapping
    k_g1p<<<GEMM1_BLOCKS + PART_BLOCKS, 256, 0, stream>>>(x, w1t, src, dst,
                                                          bucketCnt, bucket, hs);
    // 3: CSR segments + dinv
    k_build<<<NB, 512, 0, stream>>>(bucketCnt, bucket, bucketCnt + NB,
                                    rs, ce, csr, dinv);
    // 4: gather1 (+dinv[src] scaling) fused with gemm2
    k_fuse<<<GEMM1_BLOCKS, 512, 0, stream>>>(rs, ce, csr, hs, dinv, b1, w2t, hs2);
    // 5: gather2 -> out
    k_gather2<<<NN / 32, 320, 0, stream>>>(rs, ce, csr, (const __half*)hs2,
                                           dinv, b2, out);
}